// Round 1
// baseline (846.813 us; speedup 1.0000x reference)
//
#include <hip/hip_runtime.h>

typedef __attribute__((ext_vector_type(8))) short short8;
typedef __attribute__((ext_vector_type(4))) float f32x4;
typedef unsigned short u16;

// ---------------- helpers ----------------
__device__ __forceinline__ u16 f2bf(float f){
  unsigned int u = __float_as_uint(f);
  u += 0x7FFFu + ((u>>16)&1u);
  return (u16)(u>>16);
}
__device__ __forceinline__ float bf2f(u16 h){
  return __uint_as_float(((unsigned int)h)<<16);
}
__device__ __forceinline__ float sigm(float x){ return 1.f/(1.f+__expf(-x)); }

// dims
#define MDIM 2048   // B*L
#define DDIM 1024
#define NSTATE 64
#define KDIM 1024

// ---------------- weight conversion (f32 -> bf16) ----------------
// segments (element offsets): selW 1048576 | WxBC 131072 | gateW 1048576 | impW 65536 | Wout 1048576
__global__ __launch_bounds__(256) void convert_k(
    const float* __restrict__ selW, const float* __restrict__ WxBC,
    const float* __restrict__ gateW, const float* __restrict__ impW,
    const float* __restrict__ Wout,
    u16* __restrict__ dSel, u16* __restrict__ dBC, u16* __restrict__ dGate,
    u16* __restrict__ dImp, u16* __restrict__ dWout)
{
  int e = (blockIdx.x*256 + threadIdx.x)*4;
  const float4* s; u16* d;
  if (e < 1048576){ s=(const float4*)(selW+e); d=dSel+e; }
  else if (e < 1179648){ int o=e-1048576; s=(const float4*)(WxBC+o); d=dBC+o; }
  else if (e < 2228224){ int o=e-1179648; s=(const float4*)(gateW+o); d=dGate+o; }
  else if (e < 2293760){ int o=e-2228224; s=(const float4*)(impW+o); d=dImp+o; }
  else { int o=e-2293760; s=(const float4*)(Wout+o); d=dWout+o; }
  float4 v = *s;
  ushort4 ov; ov.x=f2bf(v.x); ov.y=f2bf(v.y); ov.z=f2bf(v.z); ov.w=f2bf(v.w);
  *(ushort4*)d = ov;
}

// ---------------- dtW_eff = dtW(1024x64) @ Wx[0:64](64x1024) -> bf16 (1024x1024) ----------------
__global__ __launch_bounds__(256) void dtweff_k(
    const float* __restrict__ dtW, const float* __restrict__ Wx, u16* __restrict__ dst)
{
  int j = blockIdx.x*256 + threadIdx.x;   // column 0..1023 (grid.x = 4)
  int d0 = blockIdx.y*16;                 // grid.y = 64
  float acc[16];
  #pragma unroll
  for (int i=0;i<16;++i) acc[i]=0.f;
  for (int r=0;r<64;++r){
    float wx = Wx[r*1024 + j];
    #pragma unroll
    for (int i=0;i<16;++i) acc[i] = fmaf(dtW[(d0+i)*64 + r], wx, acc[i]);
  }
  #pragma unroll
  for (int i=0;i<16;++i) dst[(size_t)(d0+i)*1024 + j] = f2bf(acc[i]);
}

// ---------------- RMSNorm: x (f32) -> xn (bf16) ----------------
__global__ __launch_bounds__(256) void rmsnorm_k(
    const float* __restrict__ x, const float* __restrict__ w, u16* __restrict__ xn)
{
  int row = blockIdx.x, tid = threadIdx.x;
  float4 xv = ((const float4*)(x + (size_t)row*DDIM))[tid];
  float s = xv.x*xv.x + xv.y*xv.y + xv.z*xv.z + xv.w*xv.w;
  #pragma unroll
  for (int m=1; m<64; m<<=1) s += __shfl_xor(s, m);
  __shared__ float red[4];
  if ((tid&63)==0) red[tid>>6] = s;
  __syncthreads();
  float tot = red[0]+red[1]+red[2]+red[3];
  float rs = rsqrtf(tot*(1.f/1024.f) + 1e-6f);
  float4 wv = ((const float4*)w)[tid];
  ushort4 o;
  o.x=f2bf(xv.x*rs*wv.x); o.y=f2bf(xv.y*rs*wv.y);
  o.z=f2bf(xv.z*rs*wv.z); o.w=f2bf(xv.w*rs*wv.w);
  ((ushort4*)(xn + (size_t)row*DDIM))[tid] = o;
}

// ---------------- MFMA GEMM: C[m,n] = sum_k X[m,k]*W[n,k], K=1024 ----------------
// tile 128x64, 4 waves (2x2), wave subtile 64x32 (4x2 fragments of 16x16)
// MODE 0: W = [selW | dtW_eff | WxB | WxC] (N=2176)
//   n<1024   : sel = sigm((v+b1[n])*b2[n]); xn2[m,n] = bf16(xn[m,n]*sel)
//   n<2048   : delta[m,n-1024] = softplus(v + b3[n-1024])
//   else     : BC[m,n-2048] = v
// MODE 1: W = [gateW | impW] (N=1088)
//   n<1024   : xn3[m,n] = xn2[m,n]*sigm(v+b1[n])
//   else     : imp[m,n-1024] = sigm(v+b2[n-1024])
// MODE 2: W = Wout (N=1024):  out[m,n] = v
template<int MODE>
__global__ __launch_bounds__(256) void gemm_bt(
    const u16* __restrict__ X, const u16* __restrict__ W,
    const float* __restrict__ b1, const float* __restrict__ b2,
    const float* __restrict__ b3, const u16* __restrict__ aux,
    u16* __restrict__ oBF, float* __restrict__ oF1, float* __restrict__ oF2)
{
  __shared__ u16 As[128*40];   // 80B rows (pad 64->80) : conflict-free-ish
  __shared__ u16 Bs[64*40];
  const int tid = threadIdx.x;
  const int wid = tid>>6, lane = tid&63;
  const int wr = wid>>1, wc = wid&1;
  const int lr = lane&15, lg = lane>>4;
  const int bm = blockIdx.y*128, bn = blockIdx.x*64;

  f32x4 acc[4][2];
  #pragma unroll
  for (int a0=0;a0<4;++a0)
    #pragma unroll
    for (int b0=0;b0<2;++b0) acc[a0][b0] = (f32x4){0.f,0.f,0.f,0.f};

  const int arow = tid>>2, aslot = tid&3;
  const u16* xs0 = X + (size_t)(bm + arow)*KDIM + aslot*8;
  const u16* xs1 = X + (size_t)(bm + 64 + arow)*KDIM + aslot*8;
  const u16* wsrc = W + (size_t)(bn + arow)*KDIM + aslot*8;
  u16* asd0 = As + arow*40 + aslot*8;
  u16* asd1 = As + (64+arow)*40 + aslot*8;
  u16* bsd  = Bs + arow*40 + aslot*8;

  for (int kt=0; kt<KDIM; kt+=32){
    uint4 va0 = *(const uint4*)(xs0 + kt);
    uint4 va1 = *(const uint4*)(xs1 + kt);
    uint4 vb  = *(const uint4*)(wsrc + kt);
    __syncthreads();
    *(uint4*)asd0 = va0;
    *(uint4*)asd1 = va1;
    *(uint4*)bsd  = vb;
    __syncthreads();
    short8 af[4], bfr[2];
    #pragma unroll
    for (int a0=0;a0<4;++a0)
      af[a0] = *(const short8*)(As + (wr*64 + a0*16 + lr)*40 + lg*8);
    #pragma unroll
    for (int b0=0;b0<2;++b0)
      bfr[b0] = *(const short8*)(Bs + (wc*32 + b0*16 + lr)*40 + lg*8);
    #pragma unroll
    for (int a0=0;a0<4;++a0)
      #pragma unroll
      for (int b0=0;b0<2;++b0)
        acc[a0][b0] = __builtin_amdgcn_mfma_f32_16x16x32_bf16(af[a0], bfr[b0], acc[a0][b0], 0, 0, 0);
  }

  // epilogue: D row = (lane>>4)*4 + i, col = lane&15  [verified m89/m91]
  const int colb = bn + wc*32;
  #pragma unroll
  for (int a0=0;a0<4;++a0){
    const int m0 = bm + wr*64 + a0*16 + lg*4;
    #pragma unroll
    for (int b0=0;b0<2;++b0){
      const int n = colb + b0*16 + lr;
      #pragma unroll
      for (int i=0;i<4;++i){
        const int m = m0 + i;
        float v = acc[a0][b0][i];
        if constexpr (MODE==0){
          if (n < 1024){
            float s = sigm((v + b1[n])*b2[n]);
            float xnv = bf2f(aux[(size_t)m*1024 + n]);
            oBF[(size_t)m*1024 + n] = f2bf(xnv*s);
          } else if (n < 2048){
            int c = n-1024;
            float t = v + b3[c];
            oF1[(size_t)m*1024 + c] = fmaxf(t,0.f) + log1pf(__expf(-fabsf(t)));
          } else {
            oF2[(size_t)m*128 + (n-2048)] = v;
          }
        } else if constexpr (MODE==1){
          if (n < 1024){
            float g = sigm(v + b1[n]);
            oF1[(size_t)m*1024 + n] = bf2f(aux[(size_t)m*1024 + n])*g;
          } else {
            oF2[(size_t)m*64 + (n-1024)] = sigm(v + b2[n-1024]);
          }
        } else {
          oF1[(size_t)m*1024 + n] = v;
        }
      }
    }
  }
}

// ---------------- selective scan: wave per (b,d), lane = n ----------------
// h_t = exp(dt*A[n])*h + dt*x_t*(B_t[n]*imp); y = sum_n h*(C_t[n]*imp)
// z[m,d] = bf16(y + x[m,d]*Dskip[d])
__global__ __launch_bounds__(64) void scan_k(
    const float* __restrict__ delta, const float* __restrict__ xn3,
    const float* __restrict__ BC, const float* __restrict__ imp,
    const float* __restrict__ A_log, const float* __restrict__ x,
    const float* __restrict__ Dskip, u16* __restrict__ z)
{
  const int bid = blockIdx.x;
  const int b = bid >> 10, d = bid & 1023;
  const int lane = threadIdx.x;
  const float A = -__expf(A_log[d*64 + lane]);
  const size_t base = (size_t)b*1024;
  const float* dp = delta + base*1024 + d;
  const float* xp = xn3   + base*1024 + d;
  const float* xr = x     + base*1024 + d;
  const float* bp = BC    + base*128  + lane;
  const float* cp = bp + 64;
  const float* ip = imp   + base*64   + lane;
  u16* zp = z + base*1024 + d;
  const float dsk = Dskip[d];
  float h = 0.f;
  #pragma unroll 2
  for (int t=0; t<1024; ++t){
    float dt = dp[(size_t)t*1024];
    float xt = xp[(size_t)t*1024];
    float bt = bp[t*128];
    float ct = cp[t*128];
    float it = ip[t*64];
    float dA = __expf(dt*A);
    h = dA*h + (dt*xt)*(bt*it);
    float p = h*(ct*it);
    p += __shfl_xor(p, 1);  p += __shfl_xor(p, 2);  p += __shfl_xor(p, 4);
    p += __shfl_xor(p, 8);  p += __shfl_xor(p, 16); p += __shfl_xor(p, 32);
    if (lane==0) zp[(size_t)t*1024] = f2bf(p + xr[(size_t)t*1024]*dsk);
  }
}

// ---------------- launch ----------------
extern "C" void kernel_launch(void* const* d_in, const int* in_sizes, int n_in,
                              void* d_out, int out_size, void* d_ws, size_t ws_size,
                              hipStream_t stream) {
  const float* x       = (const float*)d_in[0];
  const float* norm_w  = (const float*)d_in[1];
  const float* Wx      = (const float*)d_in[2];
  const float* dtW     = (const float*)d_in[3];
  const float* dtb     = (const float*)d_in[4];
  const float* A_log   = (const float*)d_in[5];
  const float* Dskip   = (const float*)d_in[6];
  const float* Wout    = (const float*)d_in[7];
  const float* selW    = (const float*)d_in[8];
  const float* selb    = (const float*)d_in[9];
  const float* sel_gate= (const float*)d_in[10];
  const float* impW    = (const float*)d_in[11];
  const float* impb    = (const float*)d_in[12];
  const float* gateW   = (const float*)d_in[13];
  const float* gateb   = (const float*)d_in[14];
  float* out = (float*)d_out;

  char* w = (char*)d_ws;
  u16*  wsA   = (u16*)(w);                       // 2176x1024 bf16 : [selW|dtW_eff|WxB|WxC]
  u16*  wsB   = (u16*)(w + 4456448);             // 1088x1024 bf16 : [gateW|impW]
  u16*  wsC   = (u16*)(w + 6684672);             // 1024x1024 bf16 : Wout
  u16*  xn    = (u16*)(w + 8781824);             // 2048x1024 bf16
  u16*  xn2   = (u16*)(w + 12976128);            // 2048x1024 bf16
  float* delta= (float*)(w + 17170432);          // 2048x1024 f32
  float* xn3  = (float*)(w + 25559040);          // 2048x1024 f32
  float* BCb  = (float*)(w + 33947648);          // 2048x128 f32
  float* impP = (float*)(w + 34996224);          // 2048x64 f32
  u16*  zb    = (u16*)(w + 35520512);            // 2048x1024 bf16  (total ~37.9MB)

  convert_k<<<3264, 256, 0, stream>>>(selW, Wx + 64*1024, gateW, impW, Wout,
                                      wsA, wsA + (size_t)2048*1024, wsB,
                                      wsB + (size_t)1024*1024, wsC);
  dtweff_k<<<dim3(4,64), 256, 0, stream>>>(dtW, Wx, wsA + (size_t)1024*1024);
  rmsnorm_k<<<2048, 256, 0, stream>>>(x, norm_w, xn);
  gemm_bt<0><<<dim3(34,16), 256, 0, stream>>>(xn, wsA, selb, sel_gate, dtb, xn,
                                              xn2, delta, BCb);
  gemm_bt<1><<<dim3(17,16), 256, 0, stream>>>(xn2, wsB, gateb, impb, nullptr, xn2,
                                              nullptr, xn3, impP);
  scan_k<<<2048, 64, 0, stream>>>(delta, xn3, BCb, impP, A_log, x, Dskip, zb);
  gemm_bt<2><<<dim3(16,16), 256, 0, stream>>>(zb, wsC, nullptr, nullptr, nullptr, nullptr,
                                              nullptr, out, nullptr);
}

// Round 3
// 338.328 us; speedup vs baseline: 2.5029x; 2.5029x over previous
//
#include <hip/hip_runtime.h>

typedef __attribute__((ext_vector_type(8))) short short8;
typedef __attribute__((ext_vector_type(4))) float f32x4;
typedef unsigned short u16;

// ---------------- helpers ----------------
__device__ __forceinline__ u16 f2bf(float f){
  unsigned int u = __float_as_uint(f);
  u += 0x7FFFu + ((u>>16)&1u);
  return (u16)(u>>16);
}
__device__ __forceinline__ float bf2f(u16 h){
  return __uint_as_float(((unsigned int)h)<<16);
}
__device__ __forceinline__ float sigm(float x){ return 1.f/(1.f+__expf(-x)); }

#define MDIM 2048
#define DDIM 1024
#define KDIM 1024
#define LOG2E 1.44269504f

// ---------------- weight conversion (f32 -> bf16) ----------------
__global__ __launch_bounds__(256) void convert_k(
    const float* __restrict__ selW, const float* __restrict__ WxBC,
    const float* __restrict__ gateW, const float* __restrict__ impW,
    const float* __restrict__ Wout,
    u16* __restrict__ dSel, u16* __restrict__ dBC, u16* __restrict__ dGate,
    u16* __restrict__ dImp, u16* __restrict__ dWout)
{
  int e = (blockIdx.x*256 + threadIdx.x)*4;
  const float4* s; u16* d;
  if (e < 1048576){ s=(const float4*)(selW+e); d=dSel+e; }
  else if (e < 1179648){ int o=e-1048576; s=(const float4*)(WxBC+o); d=dBC+o; }
  else if (e < 2228224){ int o=e-1179648; s=(const float4*)(gateW+o); d=dGate+o; }
  else if (e < 2293760){ int o=e-2228224; s=(const float4*)(impW+o); d=dImp+o; }
  else { int o=e-2293760; s=(const float4*)(Wout+o); d=dWout+o; }
  float4 v = *s;
  ushort4 ov; ov.x=f2bf(v.x); ov.y=f2bf(v.y); ov.z=f2bf(v.z); ov.w=f2bf(v.w);
  *(ushort4*)d = ov;
}

// ---------------- dtW_eff = dtW(1024x64) @ Wx[0:64](64x1024) -> bf16 ----------------
__global__ __launch_bounds__(256) void dtweff_k(
    const float* __restrict__ dtW, const float* __restrict__ Wx, u16* __restrict__ dst)
{
  int j = blockIdx.x*256 + threadIdx.x;
  int d0 = blockIdx.y*16;
  float acc[16];
  #pragma unroll
  for (int i=0;i<16;++i) acc[i]=0.f;
  for (int r=0;r<64;++r){
    float wx = Wx[r*1024 + j];
    #pragma unroll
    for (int i=0;i<16;++i) acc[i] = fmaf(dtW[(d0+i)*64 + r], wx, acc[i]);
  }
  #pragma unroll
  for (int i=0;i<16;++i) dst[(size_t)(d0+i)*1024 + j] = f2bf(acc[i]);
}

// ---------------- RMSNorm ----------------
__global__ __launch_bounds__(256) void rmsnorm_k(
    const float* __restrict__ x, const float* __restrict__ w, u16* __restrict__ xn)
{
  int row = blockIdx.x, tid = threadIdx.x;
  float4 xv = ((const float4*)(x + (size_t)row*DDIM))[tid];
  float s = xv.x*xv.x + xv.y*xv.y + xv.z*xv.z + xv.w*xv.w;
  #pragma unroll
  for (int m=1; m<64; m<<=1) s += __shfl_xor(s, m);
  __shared__ float red[4];
  if ((tid&63)==0) red[tid>>6] = s;
  __syncthreads();
  float tot = red[0]+red[1]+red[2]+red[3];
  float rs = rsqrtf(tot*(1.f/1024.f) + 1e-6f);
  float4 wv = ((const float4*)w)[tid];
  ushort4 o;
  o.x=f2bf(xv.x*rs*wv.x); o.y=f2bf(xv.y*rs*wv.y);
  o.z=f2bf(xv.z*rs*wv.z); o.w=f2bf(xv.w*rs*wv.w);
  ((ushort4*)(xn + (size_t)row*DDIM))[tid] = o;
}

// ---------------- MFMA GEMM: C[m,n] = sum_k X[m,k]*W[n,k], K=1024 ----------------
// MODE 0: W=[selW|dtW_eff|WxB|WxC] N=2176 -> xn2(bf16), delta(f32), BC(f32)
// MODE 1: W=[gateW|impW] N=1088 -> xn3(f32), BI=B*imp, CI=C*imp (f32)
// MODE 2: W=Wout N=1024 -> out(f32)
template<int MODE>
__global__ __launch_bounds__(256) void gemm_bt(
    const u16* __restrict__ X, const u16* __restrict__ W,
    const float* __restrict__ b1, const float* __restrict__ b2,
    const float* __restrict__ b3, const u16* __restrict__ aux,
    u16* __restrict__ oBF, float* __restrict__ oF1, float* __restrict__ oF2,
    float* __restrict__ oF3)
{
  __shared__ u16 As[128*40];
  __shared__ u16 Bs[64*40];
  const int tid = threadIdx.x;
  const int wid = tid>>6, lane = tid&63;
  const int wr = wid>>1, wc = wid&1;
  const int lr = lane&15, lg = lane>>4;
  const int bm = blockIdx.y*128, bn = blockIdx.x*64;

  f32x4 acc[4][2];
  #pragma unroll
  for (int a0=0;a0<4;++a0)
    #pragma unroll
    for (int b0=0;b0<2;++b0) acc[a0][b0] = (f32x4){0.f,0.f,0.f,0.f};

  const int arow = tid>>2, aslot = tid&3;
  const u16* xs0 = X + (size_t)(bm + arow)*KDIM + aslot*8;
  const u16* xs1 = X + (size_t)(bm + 64 + arow)*KDIM + aslot*8;
  const u16* wsrc = W + (size_t)(bn + arow)*KDIM + aslot*8;
  u16* asd0 = As + arow*40 + aslot*8;
  u16* asd1 = As + (64+arow)*40 + aslot*8;
  u16* bsd  = Bs + arow*40 + aslot*8;

  for (int kt=0; kt<KDIM; kt+=32){
    uint4 va0 = *(const uint4*)(xs0 + kt);
    uint4 va1 = *(const uint4*)(xs1 + kt);
    uint4 vb  = *(const uint4*)(wsrc + kt);
    __syncthreads();
    *(uint4*)asd0 = va0;
    *(uint4*)asd1 = va1;
    *(uint4*)bsd  = vb;
    __syncthreads();
    short8 af[4], bfr[2];
    #pragma unroll
    for (int a0=0;a0<4;++a0)
      af[a0] = *(const short8*)(As + (wr*64 + a0*16 + lr)*40 + lg*8);
    #pragma unroll
    for (int b0=0;b0<2;++b0)
      bfr[b0] = *(const short8*)(Bs + (wc*32 + b0*16 + lr)*40 + lg*8);
    #pragma unroll
    for (int a0=0;a0<4;++a0)
      #pragma unroll
      for (int b0=0;b0<2;++b0)
        acc[a0][b0] = __builtin_amdgcn_mfma_f32_16x16x32_bf16(af[a0], bfr[b0], acc[a0][b0], 0, 0, 0);
  }

  const int colb = bn + wc*32;
  #pragma unroll
  for (int a0=0;a0<4;++a0){
    const int m0 = bm + wr*64 + a0*16 + lg*4;
    #pragma unroll
    for (int b0=0;b0<2;++b0){
      const int n = colb + b0*16 + lr;
      #pragma unroll
      for (int i=0;i<4;++i){
        const int m = m0 + i;
        float v = acc[a0][b0][i];
        if constexpr (MODE==0){
          if (n < 1024){
            float s = sigm((v + b1[n])*b2[n]);
            float xnv = bf2f(aux[(size_t)m*1024 + n]);
            oBF[(size_t)m*1024 + n] = f2bf(xnv*s);
          } else if (n < 2048){
            int c = n-1024;
            float t = v + b3[c];
            oF1[(size_t)m*1024 + c] = fmaxf(t,0.f) + log1pf(__expf(-fabsf(t)));
          } else {
            oF2[(size_t)m*128 + (n-2048)] = v;
          }
        } else if constexpr (MODE==1){
          if (n < 1024){
            float g = sigm(v + b1[n]);
            oF1[(size_t)m*1024 + n] = bf2f(aux[(size_t)m*1024 + n])*g;
          } else {
            int c = n-1024;
            float it = sigm(v + b2[c]);
            float bb = b3[(size_t)m*128 + c];
            float cc = b3[(size_t)m*128 + 64 + c];
            oF2[(size_t)m*64 + c] = bb*it;   // BI = B*imp
            oF3[(size_t)m*64 + c] = cc*it;   // CI = C*imp
          }
        } else {
          oF1[(size_t)m*1024 + n] = v;
        }
      }
    }
  }
}

// ---------------- chunked selective scan, lane = d ----------------
// chunk size T=64, C=16 chunks. h[n],A2[n] in registers (fully unrolled).
// phase 1: local scan from h=0 -> hend[c][b][n][d] + sum_dt
__global__ __launch_bounds__(64) void scan_p1(
    const float* __restrict__ delta, const float* __restrict__ xn3,
    const float* __restrict__ BI, const float* __restrict__ A_log,
    float* __restrict__ hst, float* __restrict__ sumdt)
{
  const int lane = threadIdx.x;
  const int dg = blockIdx.x, c = blockIdx.y, b = blockIdx.z;
  const int d = dg*64 + lane;
  float A2[64], h[64];
  #pragma unroll
  for (int n0=0;n0<16;++n0){
    float4 al = *(const float4*)(A_log + (size_t)d*64 + n0*4);
    A2[n0*4+0] = -__expf(al.x)*LOG2E;
    A2[n0*4+1] = -__expf(al.y)*LOG2E;
    A2[n0*4+2] = -__expf(al.z)*LOG2E;
    A2[n0*4+3] = -__expf(al.w)*LOG2E;
  }
  #pragma unroll
  for (int n=0;n<64;++n) h[n]=0.f;
  const int row0 = b*1024 + c*64;
  float sdt = 0.f;
  for (int t=0;t<64;++t){
    const size_t row = row0 + t;
    float dt = delta[row*1024 + d];
    float xt = xn3[row*1024 + d];
    sdt += dt;
    float k = dt*xt;
    const float* bi = BI + row*64;   // wave-uniform -> s_loads
    #pragma unroll
    for (int n=0;n<64;++n)
      h[n] = exp2f(dt*A2[n])*h[n] + k*bi[n];
  }
  sumdt[(size_t)(c*2+b)*1024 + d] = sdt;
  #pragma unroll
  for (int n=0;n<64;++n)
    hst[(size_t)((c*2+b)*64 + n)*1024 + d] = h[n];
}

// phase 2: sequential prefix over 16 chunks, in-place: hst[c] <- h_start of chunk c
__global__ __launch_bounds__(256) void scan_p2(
    const float* __restrict__ A_log, const float* __restrict__ sumdt,
    float* __restrict__ hst)
{
  int gid = blockIdx.x*256 + threadIdx.x;   // 512 blocks
  int d = gid & 1023, n = (gid>>10)&63, b = gid>>16;
  float A2 = -__expf(A_log[(size_t)d*64 + n])*LOG2E;
  float carry = 0.f;
  #pragma unroll
  for (int c=0;c<16;++c){
    float P = exp2f(A2 * sumdt[(size_t)(c*2+b)*1024 + d]);
    size_t off = (size_t)((c*2+b)*64 + n)*1024 + d;
    float he = hst[off];
    hst[off] = carry;
    carry = P*carry + he;
  }
}

// phase 3: re-scan chunk from true h_start, emit z = y + x*Dskip (bf16)
__global__ __launch_bounds__(64) void scan_p3(
    const float* __restrict__ delta, const float* __restrict__ xn3,
    const float* __restrict__ BI, const float* __restrict__ CI,
    const float* __restrict__ A_log, const float* __restrict__ x,
    const float* __restrict__ Dskip, const float* __restrict__ hst,
    u16* __restrict__ z)
{
  const int lane = threadIdx.x;
  const int dg = blockIdx.x, c = blockIdx.y, b = blockIdx.z;
  const int d = dg*64 + lane;
  float A2[64], h[64];
  #pragma unroll
  for (int n0=0;n0<16;++n0){
    float4 al = *(const float4*)(A_log + (size_t)d*64 + n0*4);
    A2[n0*4+0] = -__expf(al.x)*LOG2E;
    A2[n0*4+1] = -__expf(al.y)*LOG2E;
    A2[n0*4+2] = -__expf(al.z)*LOG2E;
    A2[n0*4+3] = -__expf(al.w)*LOG2E;
  }
  #pragma unroll
  for (int n=0;n<64;++n) h[n] = hst[(size_t)((c*2+b)*64 + n)*1024 + d];
  const float dsk = Dskip[d];
  const int row0 = b*1024 + c*64;
  for (int t=0;t<64;++t){
    const size_t row = row0 + t;
    float dt = delta[row*1024 + d];
    float xt = xn3[row*1024 + d];
    float xr = x[row*1024 + d];
    float k = dt*xt;
    const float* bi = BI + row*64;
    const float* ci = CI + row*64;
    float y0=0.f, y1=0.f, y2=0.f, y3=0.f;
    #pragma unroll
    for (int n=0;n<64;n+=4){
      h[n+0] = exp2f(dt*A2[n+0])*h[n+0] + k*bi[n+0];  y0 += h[n+0]*ci[n+0];
      h[n+1] = exp2f(dt*A2[n+1])*h[n+1] + k*bi[n+1];  y1 += h[n+1]*ci[n+1];
      h[n+2] = exp2f(dt*A2[n+2])*h[n+2] + k*bi[n+2];  y2 += h[n+2]*ci[n+2];
      h[n+3] = exp2f(dt*A2[n+3])*h[n+3] + k*bi[n+3];  y3 += h[n+3]*ci[n+3];
    }
    z[row*1024 + d] = f2bf((y0+y1)+(y2+y3) + xr*dsk);
  }
}

// ---------------- launch ----------------
extern "C" void kernel_launch(void* const* d_in, const int* in_sizes, int n_in,
                              void* d_out, int out_size, void* d_ws, size_t ws_size,
                              hipStream_t stream) {
  const float* x       = (const float*)d_in[0];
  const float* norm_w  = (const float*)d_in[1];
  const float* Wx      = (const float*)d_in[2];
  const float* dtW     = (const float*)d_in[3];
  const float* dtb     = (const float*)d_in[4];
  const float* A_log   = (const float*)d_in[5];
  const float* Dskip   = (const float*)d_in[6];
  const float* Wout    = (const float*)d_in[7];
  const float* selW    = (const float*)d_in[8];
  const float* selb    = (const float*)d_in[9];
  const float* sel_gate= (const float*)d_in[10];
  const float* impW    = (const float*)d_in[11];
  const float* impb    = (const float*)d_in[12];
  const float* gateW   = (const float*)d_in[13];
  const float* gateb   = (const float*)d_in[14];
  float* out = (float*)d_out;

  char* w = (char*)d_ws;
  u16*  wsA   = (u16*)(w);                       // 2176x1024 bf16
  u16*  wsB   = (u16*)(w + 4456448);             // 1088x1024 bf16
  u16*  wsC   = (u16*)(w + 6684672);             // 1024x1024 bf16
  u16*  xn    = (u16*)(w + 8781824);             // 2048x1024 bf16
  u16*  xn2   = (u16*)(w + 12976128);            // 2048x1024 bf16
  float* hst  = (float*)(w + 8781824);           // 32x64x1024 f32 (aliases xn/xn2; used after MODE1)
  float* delta= (float*)(w + 17170432);          // 2048x1024 f32
  float* xn3  = (float*)(w + 25559040);          // 2048x1024 f32
  float* BCb  = (float*)(w + 33947648);          // 2048x128 f32
  float* BIp  = (float*)(w + 34996224);          // 2048x64 f32
  float* CIp  = (float*)(w + 35520512);          // 2048x64 f32
  u16*  zb    = (u16*)(w + 36044800);            // 2048x1024 bf16
  float* sdt  = (float*)(w + 40239104);          // 32x1024 f32  (total ~40.4MB)

  convert_k<<<3264, 256, 0, stream>>>(selW, Wx + 64*1024, gateW, impW, Wout,
                                      wsA, wsA + (size_t)2048*1024, wsB,
                                      wsB + (size_t)1024*1024, wsC);
  dtweff_k<<<dim3(4,64), 256, 0, stream>>>(dtW, Wx, wsA + (size_t)1024*1024);
  rmsnorm_k<<<2048, 256, 0, stream>>>(x, norm_w, xn);
  gemm_bt<0><<<dim3(34,16), 256, 0, stream>>>(xn, wsA, selb, sel_gate, dtb, xn,
                                              xn2, delta, BCb, nullptr);
  gemm_bt<1><<<dim3(17,16), 256, 0, stream>>>(xn2, wsB, gateb, impb, BCb, xn2,
                                              nullptr, xn3, BIp, CIp);
  scan_p1<<<dim3(16,16,2), 64, 0, stream>>>(delta, xn3, BIp, A_log, hst, sdt);
  scan_p2<<<512, 256, 0, stream>>>(A_log, sdt, hst);
  scan_p3<<<dim3(16,16,2), 64, 0, stream>>>(delta, xn3, BIp, CIp, A_log, x, Dskip, hst, zb);
  gemm_bt<2><<<dim3(16,16), 256, 0, stream>>>(zb, wsC, nullptr, nullptr, nullptr, nullptr,
                                              nullptr, out, nullptr, nullptr);
}

// Round 4
// 230.073 us; speedup vs baseline: 3.6806x; 1.4705x over previous
//
#include <hip/hip_runtime.h>

typedef __attribute__((ext_vector_type(8))) short short8;
typedef __attribute__((ext_vector_type(4))) float f32x4;
typedef unsigned short u16;

// ---------------- helpers ----------------
__device__ __forceinline__ u16 f2bf(float f){
  unsigned int u = __float_as_uint(f);
  u += 0x7FFFu + ((u>>16)&1u);
  return (u16)(u>>16);
}
__device__ __forceinline__ float bf2f(u16 h){
  return __uint_as_float(((unsigned int)h)<<16);
}
__device__ __forceinline__ float sigm(float x){ return 1.f/(1.f+__expf(-x)); }

#define MDIM 2048
#define DDIM 1024
#define KDIM 1024
#define LOG2E 1.44269504f
#define NCHUNK 32   // chunks per sequence
#define TCH 32      // timesteps per chunk

// ---------------- weight conversion (f32 -> bf16) ----------------
__global__ __launch_bounds__(256) void convert_k(
    const float* __restrict__ selW, const float* __restrict__ WxBC,
    const float* __restrict__ gateW, const float* __restrict__ impW,
    const float* __restrict__ Wout,
    u16* __restrict__ dSel, u16* __restrict__ dBC, u16* __restrict__ dGate,
    u16* __restrict__ dImp, u16* __restrict__ dWout)
{
  int e = (blockIdx.x*256 + threadIdx.x)*4;
  const float4* s; u16* d;
  if (e < 1048576){ s=(const float4*)(selW+e); d=dSel+e; }
  else if (e < 1179648){ int o=e-1048576; s=(const float4*)(WxBC+o); d=dBC+o; }
  else if (e < 2228224){ int o=e-1179648; s=(const float4*)(gateW+o); d=dGate+o; }
  else if (e < 2293760){ int o=e-2228224; s=(const float4*)(impW+o); d=dImp+o; }
  else { int o=e-2293760; s=(const float4*)(Wout+o); d=dWout+o; }
  float4 v = *s;
  ushort4 ov; ov.x=f2bf(v.x); ov.y=f2bf(v.y); ov.z=f2bf(v.z); ov.w=f2bf(v.w);
  *(ushort4*)d = ov;
}

// ---------------- dtW_eff = dtW(1024x64) @ Wx[0:64](64x1024) -> bf16 ----------------
__global__ __launch_bounds__(256) void dtweff_k(
    const float* __restrict__ dtW, const float* __restrict__ Wx, u16* __restrict__ dst)
{
  int j = blockIdx.x*256 + threadIdx.x;
  int d0 = blockIdx.y*16;
  float acc[16];
  #pragma unroll
  for (int i=0;i<16;++i) acc[i]=0.f;
  for (int r=0;r<64;++r){
    float wx = Wx[r*1024 + j];
    #pragma unroll
    for (int i=0;i<16;++i) acc[i] = fmaf(dtW[(d0+i)*64 + r], wx, acc[i]);
  }
  #pragma unroll
  for (int i=0;i<16;++i) dst[(size_t)(d0+i)*1024 + j] = f2bf(acc[i]);
}

// ---------------- RMSNorm ----------------
__global__ __launch_bounds__(256) void rmsnorm_k(
    const float* __restrict__ x, const float* __restrict__ w, u16* __restrict__ xn)
{
  int row = blockIdx.x, tid = threadIdx.x;
  float4 xv = ((const float4*)(x + (size_t)row*DDIM))[tid];
  float s = xv.x*xv.x + xv.y*xv.y + xv.z*xv.z + xv.w*xv.w;
  #pragma unroll
  for (int m=1; m<64; m<<=1) s += __shfl_xor(s, m);
  __shared__ float red[4];
  if ((tid&63)==0) red[tid>>6] = s;
  __syncthreads();
  float tot = red[0]+red[1]+red[2]+red[3];
  float rs = rsqrtf(tot*(1.f/1024.f) + 1e-6f);
  float4 wv = ((const float4*)w)[tid];
  ushort4 o;
  o.x=f2bf(xv.x*rs*wv.x); o.y=f2bf(xv.y*rs*wv.y);
  o.z=f2bf(xv.z*rs*wv.z); o.w=f2bf(xv.w*rs*wv.w);
  ((ushort4*)(xn + (size_t)row*DDIM))[tid] = o;
}

// ---------------- MFMA GEMM: C[m,n] = sum_k X[m,k]*W[n,k], K=1024 ----------------
// MODE 0: W=[selW|dtW_eff|WxB|WxC] N=2176 -> xn2(bf16), delta(f32), BC(f32)
// MODE 1: W=[gateW|impW] N=1088 -> xn3(f32), BI=B*imp, CI=C*imp (f32)
// MODE 2: W=Wout N=1024 -> out(f32)
template<int MODE>
__global__ __launch_bounds__(256) void gemm_bt(
    const u16* __restrict__ X, const u16* __restrict__ W,
    const float* __restrict__ b1, const float* __restrict__ b2,
    const float* __restrict__ b3, const u16* __restrict__ aux,
    u16* __restrict__ oBF, float* __restrict__ oF1, float* __restrict__ oF2,
    float* __restrict__ oF3)
{
  __shared__ u16 As[128*40];
  __shared__ u16 Bs[64*40];
  const int tid = threadIdx.x;
  const int wid = tid>>6, lane = tid&63;
  const int wr = wid>>1, wc = wid&1;
  const int lr = lane&15, lg = lane>>4;
  const int bm = blockIdx.y*128, bn = blockIdx.x*64;

  f32x4 acc[4][2];
  #pragma unroll
  for (int a0=0;a0<4;++a0)
    #pragma unroll
    for (int b0=0;b0<2;++b0) acc[a0][b0] = (f32x4){0.f,0.f,0.f,0.f};

  const int arow = tid>>2, aslot = tid&3;
  const u16* xs0 = X + (size_t)(bm + arow)*KDIM + aslot*8;
  const u16* xs1 = X + (size_t)(bm + 64 + arow)*KDIM + aslot*8;
  const u16* wsrc = W + (size_t)(bn + arow)*KDIM + aslot*8;
  u16* asd0 = As + arow*40 + aslot*8;
  u16* asd1 = As + (64+arow)*40 + aslot*8;
  u16* bsd  = Bs + arow*40 + aslot*8;

  for (int kt=0; kt<KDIM; kt+=32){
    uint4 va0 = *(const uint4*)(xs0 + kt);
    uint4 va1 = *(const uint4*)(xs1 + kt);
    uint4 vb  = *(const uint4*)(wsrc + kt);
    __syncthreads();
    *(uint4*)asd0 = va0;
    *(uint4*)asd1 = va1;
    *(uint4*)bsd  = vb;
    __syncthreads();
    short8 af[4], bfr[2];
    #pragma unroll
    for (int a0=0;a0<4;++a0)
      af[a0] = *(const short8*)(As + (wr*64 + a0*16 + lr)*40 + lg*8);
    #pragma unroll
    for (int b0=0;b0<2;++b0)
      bfr[b0] = *(const short8*)(Bs + (wc*32 + b0*16 + lr)*40 + lg*8);
    #pragma unroll
    for (int a0=0;a0<4;++a0)
      #pragma unroll
      for (int b0=0;b0<2;++b0)
        acc[a0][b0] = __builtin_amdgcn_mfma_f32_16x16x32_bf16(af[a0], bfr[b0], acc[a0][b0], 0, 0, 0);
  }

  const int colb = bn + wc*32;
  #pragma unroll
  for (int a0=0;a0<4;++a0){
    const int m0 = bm + wr*64 + a0*16 + lg*4;
    #pragma unroll
    for (int b0=0;b0<2;++b0){
      const int n = colb + b0*16 + lr;
      #pragma unroll
      for (int i=0;i<4;++i){
        const int m = m0 + i;
        float v = acc[a0][b0][i];
        if constexpr (MODE==0){
          if (n < 1024){
            float s = sigm((v + b1[n])*b2[n]);
            float xnv = bf2f(aux[(size_t)m*1024 + n]);
            oBF[(size_t)m*1024 + n] = f2bf(xnv*s);
          } else if (n < 2048){
            int c = n-1024;
            float t = v + b3[c];
            oF1[(size_t)m*1024 + c] = fmaxf(t,0.f) + log1pf(__expf(-fabsf(t)));
          } else {
            oF2[(size_t)m*128 + (n-2048)] = v;
          }
        } else if constexpr (MODE==1){
          if (n < 1024){
            float g = sigm(v + b1[n]);
            oF1[(size_t)m*1024 + n] = bf2f(aux[(size_t)m*1024 + n])*g;
          } else {
            int c = n-1024;
            float it = sigm(v + b2[c]);
            float bb = b3[(size_t)m*128 + c];
            float cc = b3[(size_t)m*128 + 64 + c];
            oF2[(size_t)m*64 + c] = bb*it;   // BI = B*imp
            oF3[(size_t)m*64 + c] = cc*it;   // CI = C*imp
          }
        } else {
          oF1[(size_t)m*1024 + n] = v;
        }
      }
    }
  }
}

// ---------------- chunked selective scan ----------------
// 32 chunks x 32 steps; block = 128 threads = 2 waves; wave wv owns n-states
// [wv*32, wv*32+32); lane = d. hst is bf16: [c*2+b][n][d].
// phase 1: local scan from h=0 -> h_end + sum_dt
__global__ __launch_bounds__(128) void scan_p1(
    const float* __restrict__ delta, const float* __restrict__ xn3,
    const float* __restrict__ BI, const float* __restrict__ A_log,
    u16* __restrict__ hst, float* __restrict__ sumdt)
{
  const int tid = threadIdx.x;
  const int lane = tid & 63;
  const int wv = __builtin_amdgcn_readfirstlane(tid >> 6);
  const int dg = blockIdx.x, c = blockIdx.y, b = blockIdx.z;
  const int d = dg*64 + lane;
  const int nb = wv*32;
  float A2[32], h[32];
  #pragma unroll
  for (int n0=0;n0<8;++n0){
    float4 al = *(const float4*)(A_log + (size_t)d*64 + nb + n0*4);
    A2[n0*4+0] = -__expf(al.x)*LOG2E;
    A2[n0*4+1] = -__expf(al.y)*LOG2E;
    A2[n0*4+2] = -__expf(al.z)*LOG2E;
    A2[n0*4+3] = -__expf(al.w)*LOG2E;
  }
  #pragma unroll
  for (int n=0;n<32;++n) h[n]=0.f;
  const int row0 = b*1024 + c*TCH;
  float sdt = 0.f;
  for (int t=0;t<TCH;++t){
    const size_t row = row0 + t;
    float dt = delta[row*1024 + d];
    float xt = xn3[row*1024 + d];
    sdt += dt;
    float k = dt*xt;
    const float* bi = BI + row*64 + nb;   // wave-uniform
    #pragma unroll
    for (int n=0;n<32;++n)
      h[n] = exp2f(dt*A2[n])*h[n] + k*bi[n];
  }
  if (wv==0) sumdt[(size_t)(c*2+b)*1024 + d] = sdt;
  #pragma unroll
  for (int n=0;n<32;++n)
    hst[(size_t)((c*2+b)*64 + nb + n)*1024 + d] = f2bf(h[n]);
}

// phase 2: sequential prefix over 32 chunks, in-place: hst[c] <- h_start of chunk c
__global__ __launch_bounds__(256) void scan_p2(
    const float* __restrict__ A_log, const float* __restrict__ sumdt,
    u16* __restrict__ hst)
{
  int gid = blockIdx.x*256 + threadIdx.x;   // 512 blocks -> 131072 threads
  int d = gid & 1023, n = (gid>>10)&63, b = gid>>16;
  float A2 = -__expf(A_log[(size_t)d*64 + n])*LOG2E;
  float carry = 0.f;
  #pragma unroll
  for (int c=0;c<NCHUNK;++c){
    float P = exp2f(A2 * sumdt[(size_t)(c*2+b)*1024 + d]);
    size_t off = (size_t)((c*2+b)*64 + n)*1024 + d;
    float he = bf2f(hst[off]);
    hst[off] = f2bf(carry);
    carry = P*carry + he;
  }
}

// phase 3: re-scan chunk from true h_start, emit z = y + x*Dskip (bf16)
__global__ __launch_bounds__(128) void scan_p3(
    const float* __restrict__ delta, const float* __restrict__ xn3,
    const float* __restrict__ BI, const float* __restrict__ CI,
    const float* __restrict__ A_log, const float* __restrict__ x,
    const float* __restrict__ Dskip, const u16* __restrict__ hst,
    u16* __restrict__ z)
{
  __shared__ float ypart[2][TCH][64];
  const int tid = threadIdx.x;
  const int lane = tid & 63;
  const int wv = __builtin_amdgcn_readfirstlane(tid >> 6);
  const int dg = blockIdx.x, c = blockIdx.y, b = blockIdx.z;
  const int d = dg*64 + lane;
  const int nb = wv*32;
  float A2[32], h[32];
  #pragma unroll
  for (int n0=0;n0<8;++n0){
    float4 al = *(const float4*)(A_log + (size_t)d*64 + nb + n0*4);
    A2[n0*4+0] = -__expf(al.x)*LOG2E;
    A2[n0*4+1] = -__expf(al.y)*LOG2E;
    A2[n0*4+2] = -__expf(al.z)*LOG2E;
    A2[n0*4+3] = -__expf(al.w)*LOG2E;
  }
  #pragma unroll
  for (int n=0;n<32;++n)
    h[n] = bf2f(hst[(size_t)((c*2+b)*64 + nb + n)*1024 + d]);
  const int row0 = b*1024 + c*TCH;
  for (int t=0;t<TCH;++t){
    const size_t row = row0 + t;
    float dt = delta[row*1024 + d];
    float xt = xn3[row*1024 + d];
    float k = dt*xt;
    const float* bi = BI + row*64 + nb;
    const float* ci = CI + row*64 + nb;
    float y0=0.f, y1=0.f, y2=0.f, y3=0.f;
    #pragma unroll
    for (int n=0;n<32;n+=4){
      h[n+0] = exp2f(dt*A2[n+0])*h[n+0] + k*bi[n+0];  y0 += h[n+0]*ci[n+0];
      h[n+1] = exp2f(dt*A2[n+1])*h[n+1] + k*bi[n+1];  y1 += h[n+1]*ci[n+1];
      h[n+2] = exp2f(dt*A2[n+2])*h[n+2] + k*bi[n+2];  y2 += h[n+2]*ci[n+2];
      h[n+3] = exp2f(dt*A2[n+3])*h[n+3] + k*bi[n+3];  y3 += h[n+3]*ci[n+3];
    }
    ypart[wv][t][lane] = (y0+y1)+(y2+y3);
  }
  __syncthreads();
  const int dbase = dg*64;
  #pragma unroll
  for (int i=0;i<16;++i){
    int idx = tid + i*128;
    int t = idx>>6, dl = idx&63;
    size_t row = row0 + t;
    float y = ypart[0][t][dl] + ypart[1][t][dl];
    float xr = x[row*1024 + dbase + dl];
    z[row*1024 + dbase + dl] = f2bf(y + xr*Dskip[dbase+dl]);
  }
}

// ---------------- launch ----------------
extern "C" void kernel_launch(void* const* d_in, const int* in_sizes, int n_in,
                              void* d_out, int out_size, void* d_ws, size_t ws_size,
                              hipStream_t stream) {
  const float* x       = (const float*)d_in[0];
  const float* norm_w  = (const float*)d_in[1];
  const float* Wx      = (const float*)d_in[2];
  const float* dtW     = (const float*)d_in[3];
  const float* dtb     = (const float*)d_in[4];
  const float* A_log   = (const float*)d_in[5];
  const float* Dskip   = (const float*)d_in[6];
  const float* Wout    = (const float*)d_in[7];
  const float* selW    = (const float*)d_in[8];
  const float* selb    = (const float*)d_in[9];
  const float* sel_gate= (const float*)d_in[10];
  const float* impW    = (const float*)d_in[11];
  const float* impb    = (const float*)d_in[12];
  const float* gateW   = (const float*)d_in[13];
  const float* gateb   = (const float*)d_in[14];
  float* out = (float*)d_out;

  char* w = (char*)d_ws;
  u16*  wsA   = (u16*)(w);                       // 2176x1024 bf16
  u16*  wsB   = (u16*)(w + 4456448);             // 1088x1024 bf16
  u16*  wsC   = (u16*)(w + 6684672);             // 1024x1024 bf16
  u16*  xn    = (u16*)(w + 8781824);             // 2048x1024 bf16
  u16*  xn2   = (u16*)(w + 12976128);            // 2048x1024 bf16
  u16*  hst   = (u16*)(w + 8781824);             // 64x64x1024 bf16 = 8.39MB (aliases xn/xn2; used after MODE1)
  float* delta= (float*)(w + 17170432);          // 2048x1024 f32
  float* xn3  = (float*)(w + 25559040);          // 2048x1024 f32
  float* BCb  = (float*)(w + 33947648);          // 2048x128 f32 (dead after MODE1)
  float* sdt  = (float*)(w + 33947648);          // 64x1024 f32 = 256KB (aliases BCb; written by p1)
  float* BIp  = (float*)(w + 34996224);          // 2048x64 f32
  float* CIp  = (float*)(w + 35520512);          // 2048x64 f32
  u16*  zb    = (u16*)(w + 36044800);            // 2048x1024 bf16 (end 40239104)

  convert_k<<<3264, 256, 0, stream>>>(selW, Wx + 64*1024, gateW, impW, Wout,
                                      wsA, wsA + (size_t)2048*1024, wsB,
                                      wsB + (size_t)1024*1024, wsC);
  dtweff_k<<<dim3(4,64), 256, 0, stream>>>(dtW, Wx, wsA + (size_t)1024*1024);
  rmsnorm_k<<<2048, 256, 0, stream>>>(x, norm_w, xn);
  gemm_bt<0><<<dim3(34,16), 256, 0, stream>>>(xn, wsA, selb, sel_gate, dtb, xn,
                                              xn2, delta, BCb, nullptr);
  gemm_bt<1><<<dim3(17,16), 256, 0, stream>>>(xn2, wsB, gateb, impb, BCb, xn2,
                                              nullptr, xn3, BIp, CIp);
  scan_p1<<<dim3(16,NCHUNK,2), 128, 0, stream>>>(delta, xn3, BIp, A_log, hst, sdt);
  scan_p2<<<512, 256, 0, stream>>>(A_log, sdt, hst);
  scan_p3<<<dim3(16,NCHUNK,2), 128, 0, stream>>>(delta, xn3, BIp, CIp, A_log, x, Dskip, hst, zb);
  gemm_bt<2><<<dim3(16,16), 256, 0, stream>>>(zb, wsC, nullptr, nullptr, nullptr, nullptr,
                                              nullptr, out, nullptr, nullptr);
}

// Round 5
// 181.177 us; speedup vs baseline: 4.6740x; 1.2699x over previous
//
#include <hip/hip_runtime.h>

typedef __attribute__((ext_vector_type(8))) short short8;
typedef __attribute__((ext_vector_type(4))) float f32x4;
typedef unsigned short u16;

// ---------------- helpers ----------------
__device__ __forceinline__ u16 f2bf(float f){
  unsigned int u = __float_as_uint(f);
  u += 0x7FFFu + ((u>>16)&1u);
  return (u16)(u>>16);
}
__device__ __forceinline__ float bf2f(u16 h){
  return __uint_as_float(((unsigned int)h)<<16);
}
__device__ __forceinline__ float sigm(float x){ return 1.f/(1.f+__expf(-x)); }

// raw v_exp_f32 (base-2). exp2f() lowers to an OCML call with range fixups
// (~8-10 VALU); the bare instruction is 1 trans-op, ~4cy. Denormal flush is
// fine here (underflow -> 0 decay).
__device__ __forceinline__ float fexp2(float x){
#if __has_builtin(__builtin_amdgcn_exp2f)
  return __builtin_amdgcn_exp2f(x);
#else
  float r; asm("v_exp_f32 %0, %1" : "=v"(r) : "v"(x)); return r;
#endif
}

#define MDIM 2048
#define DDIM 1024
#define KDIM 1024
#define LOG2E 1.44269504f
#define NCHUNK 32   // chunks per sequence
#define TCH 32      // timesteps per chunk

// ---------------- weight conversion (f32 -> bf16) ----------------
__global__ __launch_bounds__(256) void convert_k(
    const float* __restrict__ selW, const float* __restrict__ WxBC,
    const float* __restrict__ gateW, const float* __restrict__ impW,
    const float* __restrict__ Wout,
    u16* __restrict__ dSel, u16* __restrict__ dBC, u16* __restrict__ dGate,
    u16* __restrict__ dImp, u16* __restrict__ dWout)
{
  int e = (blockIdx.x*256 + threadIdx.x)*4;
  const float4* s; u16* d;
  if (e < 1048576){ s=(const float4*)(selW+e); d=dSel+e; }
  else if (e < 1179648){ int o=e-1048576; s=(const float4*)(WxBC+o); d=dBC+o; }
  else if (e < 2228224){ int o=e-1179648; s=(const float4*)(gateW+o); d=dGate+o; }
  else if (e < 2293760){ int o=e-2228224; s=(const float4*)(impW+o); d=dImp+o; }
  else { int o=e-2293760; s=(const float4*)(Wout+o); d=dWout+o; }
  float4 v = *s;
  ushort4 ov; ov.x=f2bf(v.x); ov.y=f2bf(v.y); ov.z=f2bf(v.z); ov.w=f2bf(v.w);
  *(ushort4*)d = ov;
}

// ---------------- dtW_eff = dtW(1024x64) @ Wx[0:64](64x1024) -> bf16 ----------------
__global__ __launch_bounds__(256) void dtweff_k(
    const float* __restrict__ dtW, const float* __restrict__ Wx, u16* __restrict__ dst)
{
  int j = blockIdx.x*256 + threadIdx.x;
  int d0 = blockIdx.y*16;
  float acc[16];
  #pragma unroll
  for (int i=0;i<16;++i) acc[i]=0.f;
  for (int r=0;r<64;++r){
    float wx = Wx[r*1024 + j];
    #pragma unroll
    for (int i=0;i<16;++i) acc[i] = fmaf(dtW[(d0+i)*64 + r], wx, acc[i]);
  }
  #pragma unroll
  for (int i=0;i<16;++i) dst[(size_t)(d0+i)*1024 + j] = f2bf(acc[i]);
}

// ---------------- RMSNorm ----------------
__global__ __launch_bounds__(256) void rmsnorm_k(
    const float* __restrict__ x, const float* __restrict__ w, u16* __restrict__ xn)
{
  int row = blockIdx.x, tid = threadIdx.x;
  float4 xv = ((const float4*)(x + (size_t)row*DDIM))[tid];
  float s = xv.x*xv.x + xv.y*xv.y + xv.z*xv.z + xv.w*xv.w;
  #pragma unroll
  for (int m=1; m<64; m<<=1) s += __shfl_xor(s, m);
  __shared__ float red[4];
  if ((tid&63)==0) red[tid>>6] = s;
  __syncthreads();
  float tot = red[0]+red[1]+red[2]+red[3];
  float rs = rsqrtf(tot*(1.f/1024.f) + 1e-6f);
  float4 wv = ((const float4*)w)[tid];
  ushort4 o;
  o.x=f2bf(xv.x*rs*wv.x); o.y=f2bf(xv.y*rs*wv.y);
  o.z=f2bf(xv.z*rs*wv.z); o.w=f2bf(xv.w*rs*wv.w);
  ((ushort4*)(xn + (size_t)row*DDIM))[tid] = o;
}

// ---------------- MFMA GEMM: C[m,n] = sum_k X[m,k]*W[n,k], K=1024 ----------------
// MODE 0: W=[selW|dtW_eff|WxB|WxC] N=2176 -> xn2(bf16), delta(f32), BC(f32)
// MODE 1: W=[gateW|impW] N=1088 -> xn3(f32), BI=B*imp, CI=C*imp (f32)
// MODE 2: W=Wout N=1024 -> out(f32)
template<int MODE>
__global__ __launch_bounds__(256) void gemm_bt(
    const u16* __restrict__ X, const u16* __restrict__ W,
    const float* __restrict__ b1, const float* __restrict__ b2,
    const float* __restrict__ b3, const u16* __restrict__ aux,
    u16* __restrict__ oBF, float* __restrict__ oF1, float* __restrict__ oF2,
    float* __restrict__ oF3)
{
  __shared__ u16 As[128*40];
  __shared__ u16 Bs[64*40];
  const int tid = threadIdx.x;
  const int wid = tid>>6, lane = tid&63;
  const int wr = wid>>1, wc = wid&1;
  const int lr = lane&15, lg = lane>>4;
  const int bm = blockIdx.y*128, bn = blockIdx.x*64;

  f32x4 acc[4][2];
  #pragma unroll
  for (int a0=0;a0<4;++a0)
    #pragma unroll
    for (int b0=0;b0<2;++b0) acc[a0][b0] = (f32x4){0.f,0.f,0.f,0.f};

  const int arow = tid>>2, aslot = tid&3;
  const u16* xs0 = X + (size_t)(bm + arow)*KDIM + aslot*8;
  const u16* xs1 = X + (size_t)(bm + 64 + arow)*KDIM + aslot*8;
  const u16* wsrc = W + (size_t)(bn + arow)*KDIM + aslot*8;
  u16* asd0 = As + arow*40 + aslot*8;
  u16* asd1 = As + (64+arow)*40 + aslot*8;
  u16* bsd  = Bs + arow*40 + aslot*8;

  for (int kt=0; kt<KDIM; kt+=32){
    uint4 va0 = *(const uint4*)(xs0 + kt);
    uint4 va1 = *(const uint4*)(xs1 + kt);
    uint4 vb  = *(const uint4*)(wsrc + kt);
    __syncthreads();
    *(uint4*)asd0 = va0;
    *(uint4*)asd1 = va1;
    *(uint4*)bsd  = vb;
    __syncthreads();
    short8 af[4], bfr[2];
    #pragma unroll
    for (int a0=0;a0<4;++a0)
      af[a0] = *(const short8*)(As + (wr*64 + a0*16 + lr)*40 + lg*8);
    #pragma unroll
    for (int b0=0;b0<2;++b0)
      bfr[b0] = *(const short8*)(Bs + (wc*32 + b0*16 + lr)*40 + lg*8);
    #pragma unroll
    for (int a0=0;a0<4;++a0)
      #pragma unroll
      for (int b0=0;b0<2;++b0)
        acc[a0][b0] = __builtin_amdgcn_mfma_f32_16x16x32_bf16(af[a0], bfr[b0], acc[a0][b0], 0, 0, 0);
  }

  const int colb = bn + wc*32;
  #pragma unroll
  for (int a0=0;a0<4;++a0){
    const int m0 = bm + wr*64 + a0*16 + lg*4;
    #pragma unroll
    for (int b0=0;b0<2;++b0){
      const int n = colb + b0*16 + lr;
      #pragma unroll
      for (int i=0;i<4;++i){
        const int m = m0 + i;
        float v = acc[a0][b0][i];
        if constexpr (MODE==0){
          if (n < 1024){
            float s = sigm((v + b1[n])*b2[n]);
            float xnv = bf2f(aux[(size_t)m*1024 + n]);
            oBF[(size_t)m*1024 + n] = f2bf(xnv*s);
          } else if (n < 2048){
            int c = n-1024;
            float t = v + b3[c];
            oF1[(size_t)m*1024 + c] = fmaxf(t,0.f) + log1pf(__expf(-fabsf(t)));
          } else {
            oF2[(size_t)m*128 + (n-2048)] = v;
          }
        } else if constexpr (MODE==1){
          if (n < 1024){
            float g = sigm(v + b1[n]);
            oF1[(size_t)m*1024 + n] = bf2f(aux[(size_t)m*1024 + n])*g;
          } else {
            int c = n-1024;
            float it = sigm(v + b2[c]);
            float bb = b3[(size_t)m*128 + c];
            float cc = b3[(size_t)m*128 + 64 + c];
            oF2[(size_t)m*64 + c] = bb*it;   // BI = B*imp
            oF3[(size_t)m*64 + c] = cc*it;   // CI = C*imp
          }
        } else {
          oF1[(size_t)m*1024 + n] = v;
        }
      }
    }
  }
}

// ---------------- chunked selective scan ----------------
// 32 chunks x 32 steps; block = 256 threads = 4 waves; wave wv owns n-states
// [wv*16, wv*16+16); lane = d. hst is bf16: [c*2+b][n][d].
// phase 1: local scan from h=0 -> h_end + sum_dt
__global__ __launch_bounds__(256) void scan_p1(
    const float* __restrict__ delta, const float* __restrict__ xn3,
    const float* __restrict__ BI, const float* __restrict__ A_log,
    u16* __restrict__ hst, float* __restrict__ sumdt)
{
  const int tid = threadIdx.x;
  const int lane = tid & 63;
  const int wv = __builtin_amdgcn_readfirstlane(tid >> 6);
  const int dg = blockIdx.x, c = blockIdx.y, b = blockIdx.z;
  const int d = dg*64 + lane;
  const int nb = wv*16;
  float A2[16], h[16];
  #pragma unroll
  for (int n0=0;n0<4;++n0){
    float4 al = *(const float4*)(A_log + (size_t)d*64 + nb + n0*4);
    A2[n0*4+0] = -__expf(al.x)*LOG2E;
    A2[n0*4+1] = -__expf(al.y)*LOG2E;
    A2[n0*4+2] = -__expf(al.z)*LOG2E;
    A2[n0*4+3] = -__expf(al.w)*LOG2E;
  }
  #pragma unroll
  for (int n=0;n<16;++n) h[n]=0.f;
  const int row0 = b*1024 + c*TCH;
  float sdt = 0.f;
  for (int t=0;t<TCH;++t){
    const size_t row = row0 + t;
    float dt = delta[row*1024 + d];
    float xt = xn3[row*1024 + d];
    sdt += dt;
    float k = dt*xt;
    const float* bi = BI + row*64 + nb;   // wave-uniform -> s_loads
    #pragma unroll
    for (int n=0;n<16;++n)
      h[n] = fexp2(dt*A2[n])*h[n] + k*bi[n];
  }
  if (wv==0) sumdt[(size_t)(c*2+b)*1024 + d] = sdt;
  #pragma unroll
  for (int n=0;n<16;++n)
    hst[(size_t)((c*2+b)*64 + nb + n)*1024 + d] = f2bf(h[n]);
}

// phase 2: sequential prefix over 32 chunks, in-place: hst[c] <- h_start of chunk c
__global__ __launch_bounds__(256) void scan_p2(
    const float* __restrict__ A_log, const float* __restrict__ sumdt,
    u16* __restrict__ hst)
{
  int gid = blockIdx.x*256 + threadIdx.x;   // 512 blocks -> 131072 threads
  int d = gid & 1023, n = (gid>>10)&63, b = gid>>16;
  float A2 = -__expf(A_log[(size_t)d*64 + n])*LOG2E;
  float carry = 0.f;
  #pragma unroll
  for (int c=0;c<NCHUNK;++c){
    float P = fexp2(A2 * sumdt[(size_t)(c*2+b)*1024 + d]);
    size_t off = (size_t)((c*2+b)*64 + n)*1024 + d;
    float he = bf2f(hst[off]);
    hst[off] = f2bf(carry);
    carry = P*carry + he;
  }
}

// phase 3: re-scan chunk from true h_start, emit z = y + x*Dskip (bf16)
__global__ __launch_bounds__(256) void scan_p3(
    const float* __restrict__ delta, const float* __restrict__ xn3,
    const float* __restrict__ BI, const float* __restrict__ CI,
    const float* __restrict__ A_log, const float* __restrict__ x,
    const float* __restrict__ Dskip, const u16* __restrict__ hst,
    u16* __restrict__ z)
{
  __shared__ float ypart[4][TCH][64];
  const int tid = threadIdx.x;
  const int lane = tid & 63;
  const int wv = __builtin_amdgcn_readfirstlane(tid >> 6);
  const int dg = blockIdx.x, c = blockIdx.y, b = blockIdx.z;
  const int d = dg*64 + lane;
  const int nb = wv*16;
  float A2[16], h[16];
  #pragma unroll
  for (int n0=0;n0<4;++n0){
    float4 al = *(const float4*)(A_log + (size_t)d*64 + nb + n0*4);
    A2[n0*4+0] = -__expf(al.x)*LOG2E;
    A2[n0*4+1] = -__expf(al.y)*LOG2E;
    A2[n0*4+2] = -__expf(al.z)*LOG2E;
    A2[n0*4+3] = -__expf(al.w)*LOG2E;
  }
  #pragma unroll
  for (int n=0;n<16;++n)
    h[n] = bf2f(hst[(size_t)((c*2+b)*64 + nb + n)*1024 + d]);
  const int row0 = b*1024 + c*TCH;
  for (int t=0;t<TCH;++t){
    const size_t row = row0 + t;
    float dt = delta[row*1024 + d];
    float xt = xn3[row*1024 + d];
    float k = dt*xt;
    const float* bi = BI + row*64 + nb;
    const float* ci = CI + row*64 + nb;
    float y0=0.f, y1=0.f, y2=0.f, y3=0.f;
    #pragma unroll
    for (int n=0;n<16;n+=4){
      h[n+0] = fexp2(dt*A2[n+0])*h[n+0] + k*bi[n+0];  y0 += h[n+0]*ci[n+0];
      h[n+1] = fexp2(dt*A2[n+1])*h[n+1] + k*bi[n+1];  y1 += h[n+1]*ci[n+1];
      h[n+2] = fexp2(dt*A2[n+2])*h[n+2] + k*bi[n+2];  y2 += h[n+2]*ci[n+2];
      h[n+3] = fexp2(dt*A2[n+3])*h[n+3] + k*bi[n+3];  y3 += h[n+3]*ci[n+3];
    }
    ypart[wv][t][lane] = (y0+y1)+(y2+y3);
  }
  __syncthreads();
  const int dbase = dg*64;
  #pragma unroll
  for (int i=0;i<8;++i){
    int idx = tid + i*256;
    int t = idx>>6, dl = idx&63;
    size_t row = row0 + t;
    float y = ypart[0][t][dl] + ypart[1][t][dl] + ypart[2][t][dl] + ypart[3][t][dl];
    float xr = x[row*1024 + dbase + dl];
    z[row*1024 + dbase + dl] = f2bf(y + xr*Dskip[dbase+dl]);
  }
}

// ---------------- launch ----------------
extern "C" void kernel_launch(void* const* d_in, const int* in_sizes, int n_in,
                              void* d_out, int out_size, void* d_ws, size_t ws_size,
                              hipStream_t stream) {
  const float* x       = (const float*)d_in[0];
  const float* norm_w  = (const float*)d_in[1];
  const float* Wx      = (const float*)d_in[2];
  const float* dtW     = (const float*)d_in[3];
  const float* dtb     = (const float*)d_in[4];
  const float* A_log   = (const float*)d_in[5];
  const float* Dskip   = (const float*)d_in[6];
  const float* Wout    = (const float*)d_in[7];
  const float* selW    = (const float*)d_in[8];
  const float* selb    = (const float*)d_in[9];
  const float* sel_gate= (const float*)d_in[10];
  const float* impW    = (const float*)d_in[11];
  const float* impb    = (const float*)d_in[12];
  const float* gateW   = (const float*)d_in[13];
  const float* gateb   = (const float*)d_in[14];
  float* out = (float*)d_out;

  char* w = (char*)d_ws;
  u16*  wsA   = (u16*)(w);                       // 2176x1024 bf16
  u16*  wsB   = (u16*)(w + 4456448);             // 1088x1024 bf16
  u16*  wsC   = (u16*)(w + 6684672);             // 1024x1024 bf16
  u16*  xn    = (u16*)(w + 8781824);             // 2048x1024 bf16
  u16*  xn2   = (u16*)(w + 12976128);            // 2048x1024 bf16
  u16*  hst   = (u16*)(w + 8781824);             // 64x64x1024 bf16 = 8.39MB (aliases xn/xn2; used after MODE1)
  float* delta= (float*)(w + 17170432);          // 2048x1024 f32
  float* xn3  = (float*)(w + 25559040);          // 2048x1024 f32
  float* BCb  = (float*)(w + 33947648);          // 2048x128 f32 (dead after MODE1)
  float* sdt  = (float*)(w + 33947648);          // 64x1024 f32 = 256KB (aliases BCb; written by p1)
  float* BIp  = (float*)(w + 34996224);          // 2048x64 f32
  float* CIp  = (float*)(w + 35520512);          // 2048x64 f32
  u16*  zb    = (u16*)(w + 36044800);            // 2048x1024 bf16 (end 40239104)

  convert_k<<<3264, 256, 0, stream>>>(selW, Wx + 64*1024, gateW, impW, Wout,
                                      wsA, wsA + (size_t)2048*1024, wsB,
                                      wsB + (size_t)1024*1024, wsC);
  dtweff_k<<<dim3(4,64), 256, 0, stream>>>(dtW, Wx, wsA + (size_t)1024*1024);
  rmsnorm_k<<<2048, 256, 0, stream>>>(x, norm_w, xn);
  gemm_bt<0><<<dim3(34,16), 256, 0, stream>>>(xn, wsA, selb, sel_gate, dtb, xn,
                                              xn2, delta, BCb, nullptr);
  gemm_bt<1><<<dim3(17,16), 256, 0, stream>>>(xn2, wsB, gateb, impb, BCb, xn2,
                                              nullptr, xn3, BIp, CIp);
  scan_p1<<<dim3(16,NCHUNK,2), 256, 0, stream>>>(delta, xn3, BIp, A_log, hst, sdt);
  scan_p2<<<512, 256, 0, stream>>>(A_log, sdt, hst);
  scan_p3<<<dim3(16,NCHUNK,2), 256, 0, stream>>>(delta, xn3, BIp, CIp, A_log, x, Dskip, hst, zb);
  gemm_bt<2><<<dim3(16,16), 256, 0, stream>>>(zb, wsC, nullptr, nullptr, nullptr, nullptr,
                                              nullptr, out, nullptr, nullptr);
}